// Round 8
// baseline (7485.856 us; speedup 1.0000x reference)
//
#include <hip/hip_runtime.h>

// Residual VQ: N=65536, D=256, K=1024, 4 codebooks.
// Inputs: f32 (runtime-detected; bf16 fallback): z [N][D], cb [4][K][D].
// Output: FLOAT32 concat: quant_sum [N][D] | inds [N][4] | loss [1].
//
// Round 16: LDS-BANDWIDTH model (finally fits all rounds R9-R15):
// old structure read B as 96 LDS-cyc + A as 48 per wave per dd = 1152/CU
// vs 560 VALU => 2.06x LDS-oversubscribed => ~2.0ms LDS floor. R13's null
// (instr count changed, bytes didn't) and occupancy nulls all follow.
// FIX: B leaves LDS entirely. Codebook is static; each WAVE reads a
// wave-uniform code slice => scalar/SMEM path (s_load via readfirstlane-
// uniform addresses), B consumed as the SGPR operand of v_fmac_f32.
//  - lane=row: TM=64, 1024 blocks, 4 waves/block; wave w streams codes
//    [w*256,(w+1)*256) in tiles of 8; acc[8]/lane; A = 1 ds_read_b128/dd
//    shared by 32 FMA => per-CU LDS 96 cyc vs VALU ~560 => VALU-bound.
//  - No Wld, no staging, no staging barriers (3 barriers/cb total).
//  - q via global RMW (R12-proven bit-chain: cb0 writes 0+s, else r+add+w).
//  - Scoring chain EXACT: sequential fmaf d=0..255 per (row,code),
//    np-pairwise r2/w2, dist=fl(fl(r2-2dot)+w2), first-min ties (per-wave
//    ascending c; cross-wave strict-< merge in wave order == global
//    first-min since wave ranges are ordered), elementwise ST dance,
//    f64 loss tree.
//  - Predicted: dur ~1400-1900us rocprof, conflicts <1e8, FETCH ~280MB,
//    WRITE ~265MB, VGPR<=128, watch SGPR.
// Rules: no __shfl, single instantiation, LDS-tree reductions, canary.

#define N_TOK 65536
#define DIM   256
#define KCB   1024
#define NCBK  4

#define TM  64          // rows per block (= lanes)
#define RST 260         // f32 LDS stride, residual rows (16B-aligned)

#define QS_F   ((size_t)N_TOK * DIM)             // 16777216 f32 elements
#define IDX_F  QS_F
#define IDXE_F (IDX_F + (size_t)N_TOK * NCBK)    // 17039360
#define LOSS_F IDXE_F                            // 17039360

// d_ws: float w2f[4096] @0 | double partials[1024] @16384 | int flags[2] @32768
#define WS_PART_OFF 16384
#define WS_FLAG_OFF 32768

typedef unsigned short u16;
typedef unsigned int   u32;

__device__ __forceinline__ float bf2f(u32 h) { return __uint_as_float(h << 16); }

__device__ __forceinline__ float getv(const void* base, int f32in, size_t elt) {
    if (f32in) return ((const float*)base)[elt];
    return bf2f(((const u16*)base)[elt]);
}

// All call sites pass elt % 8 == 0 => 32B (f32) / 16B (bf16) aligned.
__device__ __forceinline__ void load8(const void* base, int f32in, size_t elt,
                                      float* f) {
    if (f32in) {
        const float4* p = (const float4*)((const float*)base + elt);
        float4 a = p[0], b = p[1];
        f[0] = a.x; f[1] = a.y; f[2] = a.z; f[3] = a.w;
        f[4] = b.x; f[5] = b.y; f[6] = b.z; f[7] = b.w;
    } else {
        uint4 q = *(const uint4*)((const u16*)base + elt);
        f[0] = bf2f(q.x & 0xffffu); f[1] = bf2f(q.x >> 16);
        f[2] = bf2f(q.y & 0xffffu); f[3] = bf2f(q.y >> 16);
        f[4] = bf2f(q.z & 0xffffu); f[5] = bf2f(q.z >> 16);
        f[6] = bf2f(q.w & 0xffffu); f[7] = bf2f(q.w >> 16);
    }
}

// canary: stamp f32 index region + loss with 512.0f (decodable no-op signal)
__global__ void canary_kernel(float* out) {
    int gid = blockIdx.x * 256 + threadIdx.x;
    size_t pos = IDX_F + (size_t)gid;
    if (pos < IDXE_F) out[pos] = 512.0f;
    if (gid == 0) out[LOSS_F] = 512.0f;
}

// dtype detect (bf16 vs f32), proven in rounds 7/8
__global__ void detect_kernel(const u16* z16, const u16* cb16, int* flags) {
    __shared__ int s0[256], s1[256];
    int tid = threadIdx.x;
    u32 a = z16[tid],  ea = (a >> 7) & 0xffu;
    u32 b = cb16[tid], eb = (b >> 7) & 0xffu;
    s0[tid] = ((ea >= 90u && ea <= 140u) || ((a & 0x7fffu) == 0u)) ? 1 : 0;
    s1[tid] = ((eb >= 90u && eb <= 140u) || ((b & 0x7fffu) == 0u)) ? 1 : 0;
    __syncthreads();
    for (int st = 128; st > 0; st >>= 1) {
        if (tid < st) { s0[tid] += s0[tid + st]; s1[tid] += s1[tid + st]; }
        __syncthreads();
    }
    if (tid == 0) { flags[0] = (s0[0] < 218) ? 1 : 0;   // 1 => f32
                    flags[1] = (s1[0] < 218) ? 1 : 0; }
}

// numpy pairwise sum-of-squares, one 128 block, AVX512 W=16 order
__device__ __forceinline__ float np128_sq_g(const void* base, int f32in, size_t off) {
    float S[16];
    #pragma unroll
    for (int l = 0; l < 16; ++l) {
        float A[8];
        #pragma unroll
        for (int j = 0; j < 8; ++j) {
            float x = getv(base, f32in, off + 16 * j + l);
            A[j] = x * x;
        }
        S[l] = ((A[0] + A[1]) + (A[2] + A[3])) + ((A[4] + A[5]) + (A[6] + A[7]));
    }
    float B1[8], B2[4];
    #pragma unroll
    for (int l = 0; l < 8; ++l) B1[l] = S[l] + S[l + 8];
    #pragma unroll
    for (int l = 0; l < 4; ++l) B2[l] = B1[l] + B1[l + 4];
    return (B2[0] + B2[2]) + (B2[1] + B2[3]);
}

__device__ __forceinline__ float np128_sq_lds(const float* a) {
    float S[16];
    #pragma unroll
    for (int l = 0; l < 16; ++l) {
        float A[8];
        #pragma unroll
        for (int j = 0; j < 8; ++j) { float x = a[16 * j + l]; A[j] = x * x; }
        S[l] = ((A[0] + A[1]) + (A[2] + A[3])) + ((A[4] + A[5]) + (A[6] + A[7]));
    }
    float B1[8], B2[4];
    #pragma unroll
    for (int l = 0; l < 8; ++l) B1[l] = S[l] + S[l + 8];
    #pragma unroll
    for (int l = 0; l < 4; ++l) B2[l] = B1[l] + B1[l + 4];
    return (B2[0] + B2[2]) + (B2[1] + B2[3]);
}

__global__ void w2_kernel(const void* cbs, float* w2f, const int* flags) {
    int kf = blockIdx.x * 256 + threadIdx.x;      // 0..4095
    const int fc = flags[1];
    size_t base = (size_t)kf * DIM;
    w2f[kf] = np128_sq_g(cbs, fc, base) + np128_sq_g(cbs, fc, base + 128);
}

// ---- wave-uniform B loaders (8 codes x 4 d), f32 and bf16 variants ----
#define LOADB_F32(B, DDX) {                                                  \
    const float* _p = cbf + (size_t)(DDX) * 4;                               \
    B[0] = *(const float4*)(_p);                                             \
    B[1] = *(const float4*)(_p + DIM);                                       \
    B[2] = *(const float4*)(_p + 2 * DIM);                                   \
    B[3] = *(const float4*)(_p + 3 * DIM);                                   \
    B[4] = *(const float4*)(_p + 4 * DIM);                                   \
    B[5] = *(const float4*)(_p + 5 * DIM);                                   \
    B[6] = *(const float4*)(_p + 6 * DIM);                                   \
    B[7] = *(const float4*)(_p + 7 * DIM); }

__device__ __forceinline__ float4 bf4(const u16* p) {
    uint2 r = *(const uint2*)p;
    return make_float4(bf2f(r.x & 0xffffu), bf2f(r.x >> 16),
                       bf2f(r.y & 0xffffu), bf2f(r.y >> 16));
}

#define LOADB_BF16(B, DDX) {                                                 \
    const u16* _p = cbh + (size_t)(DDX) * 4;                                 \
    B[0] = bf4(_p);           B[1] = bf4(_p + DIM);                          \
    B[2] = bf4(_p + 2 * DIM); B[3] = bf4(_p + 3 * DIM);                      \
    B[4] = bf4(_p + 4 * DIM); B[5] = bf4(_p + 5 * DIM);                      \
    B[6] = bf4(_p + 6 * DIM); B[7] = bf4(_p + 7 * DIM); }

// tile loop: 32 tiles of 8 codes; double-buffered B; d ascending fmaf chain
#define TILE_LOOP(LOADB)                                                     \
    for (int tile = 0; tile < 32; ++tile) {                                  \
        const int code0 = wv * 256 + tile * 8;                               \
        const float* cbf = (const float*)cbs + cbW + (size_t)code0 * DIM;    \
        const u16*   cbh = (const u16*)cbs + cbW + (size_t)code0 * DIM;      \
        (void)cbf; (void)cbh;                                                \
        float acc[8];                                                        \
        _Pragma("unroll")                                                    \
        for (int j = 0; j < 8; ++j) acc[j] = 0.f;                            \
        float4 bA[8], bB[8];                                                 \
        LOADB(bA, 0)                                                         \
        _Pragma("unroll 2")                                                  \
        for (int dd2 = 0; dd2 < 32; ++dd2) {                                 \
            const int d0 = dd2 * 2;                                          \
            LOADB(bB, d0 + 1)                                                \
            {                                                                \
                const float4 av = *(const float4*)&Rld[lane * RST + d0 * 4]; \
                _Pragma("unroll")                                            \
                for (int j = 0; j < 8; ++j) {                                \
                    float s = acc[j];                                        \
                    s = fmaf(av.x, bA[j].x, s);                              \
                    s = fmaf(av.y, bA[j].y, s);                              \
                    s = fmaf(av.z, bA[j].z, s);                              \
                    s = fmaf(av.w, bA[j].w, s);                              \
                    acc[j] = s;                                              \
                }                                                            \
            }                                                                \
            LOADB(bA, (d0 + 2) & 63)                                         \
            {                                                                \
                const float4 av =                                            \
                    *(const float4*)&Rld[lane * RST + (d0 + 1) * 4];         \
                _Pragma("unroll")                                            \
                for (int j = 0; j < 8; ++j) {                                \
                    float s = acc[j];                                        \
                    s = fmaf(av.x, bB[j].x, s);                              \
                    s = fmaf(av.y, bB[j].y, s);                              \
                    s = fmaf(av.z, bB[j].z, s);                              \
                    s = fmaf(av.w, bB[j].w, s);                              \
                    acc[j] = s;                                              \
                }                                                            \
            }                                                                \
        }                                                                    \
        _Pragma("unroll")                                                    \
        for (int j = 0; j < 8; ++j) {                                        \
            const int c = code0 + j;                                         \
            const float w2k = w2c[c];                                        \
            const float t2 = r2v - 2.0f * acc[j];                            \
            const float dist = t2 + w2k;                                     \
            if (dist < bval || (dist == bval && c < bidx)) {                 \
                bval = dist; bidx = c;                                       \
            }                                                                \
        }                                                                    \
    }

__global__ __launch_bounds__(256, 2)
void rq_kernel(const void* z, const void* cbs, const float* w2f,
               float* out, double* partials, const int* flags) {
    __shared__ float  Rld[TM * RST];        // 66560 B
    __shared__ float  candv[4 * 64];        //  1024 B
    __shared__ int    candi[4 * 64];        //  1024 B
    __shared__ int    bestk[TM];            //   256 B
    __shared__ double dred[256];            //  2048 B => 70912 B (2 blk/CU)

    const int fz = flags[0], fc = flags[1];
    const int tid  = threadIdx.x;
    const int lane = tid & 63;                                   // = row for scoring
    const int wv   = __builtin_amdgcn_readfirstlane(tid >> 6);   // wave 0..3, uniform
    const int row0 = blockIdx.x * TM;

    // dance mapping: 4 threads per row, 64 d each
    const int drow = tid >> 2;
    const int dseg = (tid & 3) * 64;

    // stage z -> Rld (64 rows x 256)
    for (int it = 0; it < 8; ++it) {
        int flat = it * 256 + tid;
        int r = flat >> 5, c8 = flat & 31;
        float f[8];
        load8(z, fz, (size_t)(row0 + r) * DIM + c8 * 8, f);
        int base = r * RST + c8 * 8;
        #pragma unroll
        for (int e = 0; e < 8; ++e) Rld[base + e] = f[e];
    }
    double lsum = 0.0;

    for (int cb = 0; cb < NCBK; ++cb) {
        const size_t cbW = (size_t)cb * KCB * DIM;
        const float* w2c = w2f + cb * KCB;

        __syncthreads();                     // Rld settled (stage or prev dance)

        // r2 for this lane's row (all waves compute identically; no LDS share)
        const float* arow = &Rld[lane * RST];
        const float r2v = np128_sq_lds(arow) + np128_sq_lds(arow + 128);

        float bval = __uint_as_float(0x7f7fffffu);
        int   bidx = 0;

        if (fc) { TILE_LOOP(LOADB_F32) }
        else    { TILE_LOOP(LOADB_BF16) }

        // cross-wave argmin merge. wave ranges ascend => strict < keeps the
        // lowest code index on value ties (== reference first-min).
        candv[wv * 64 + lane] = bval;
        candi[wv * 64 + lane] = bidx;
        __syncthreads();                     // B1
        {
            float best = candv[lane];
            int   bi   = candi[lane];
            #pragma unroll
            for (int w = 1; w < 4; ++w) {
                float v = candv[w * 64 + lane];
                int  ci = candi[w * 64 + lane];
                if (v < best) { best = v; bi = ci; }
            }
            if (tid < 64) {
                bestk[lane] = bi;
                size_t pos = IDX_F + (size_t)(row0 + lane) * NCBK + cb;
                if (pos < IDXE_F) out[pos] = (float)bi;
            }
        }
        __syncthreads();                     // B2: bestk visible

        // straight-through dance, elementwise f32 (np bit order):
        // t = zq - r; s = r + t; r' = r - s; q += s; loss += t^2
        // q lives in GLOBAL out[]: cb==0 writes (0+s), else read+add+write
        // (same f32 chain (((0+s1)+s2)+s3)+s4; per-thread-private RMW).
        {
            const int kb = bestk[drow];
            for (int it = 0; it < 8; ++it) {
                const int off = dseg + it * 8;
                float f[8];
                load8(cbs, fc, cbW + (size_t)kb * DIM + off, f);
                const int    base = drow * RST + off;
                const size_t pos  = (size_t)(row0 + drow) * DIM + off;
                float qv[8];
                if (cb == 0) {
                    #pragma unroll
                    for (int e = 0; e < 8; ++e) qv[e] = 0.0f;
                } else {
                    float4 o0 = *(const float4*)&out[pos];
                    float4 o1 = *(const float4*)&out[pos + 4];
                    qv[0] = o0.x; qv[1] = o0.y; qv[2] = o0.z; qv[3] = o0.w;
                    qv[4] = o1.x; qv[5] = o1.y; qv[6] = o1.z; qv[7] = o1.w;
                }
                #pragma unroll
                for (int e = 0; e < 8; ++e) {
                    float rv = Rld[base + e];
                    float t  = f[e] - rv;
                    float s  = rv + t;
                    float rn = rv - s;
                    Rld[base + e] = rn;
                    qv[e] = qv[e] + s;
                    lsum += (double)t * (double)t;
                }
                *(float4*)&out[pos]     = make_float4(qv[0], qv[1], qv[2], qv[3]);
                *(float4*)&out[pos + 4] = make_float4(qv[4], qv[5], qv[6], qv[7]);
            }
        }
        __syncthreads();                     // B3: dance done before next cb
    }

    // loss: per-block f64 LDS tree -> partials[block]
    dred[tid] = lsum;
    __syncthreads();
    for (int s = 128; s > 0; s >>= 1) {
        if (tid < s) dred[tid] += dred[tid + s];
        __syncthreads();
    }
    if (tid == 0) partials[blockIdx.x] = dred[0];
}

__global__ void loss_final(const double* partials, float* out) {
    __shared__ double sred[256];
    int tid = threadIdx.x;
    double s = 0.0;
    for (int q = 0; q < 4; ++q) s += partials[tid + 256 * q];
    sred[tid] = s;
    __syncthreads();
    for (int st = 128; st > 0; st >>= 1) {
        if (tid < st) sred[tid] += sred[tid + st];
        __syncthreads();
    }
    if (tid == 0)
        out[LOSS_F] = (float)(2.0 * sred[0] / 16777216.0);  // 2*S/(N*D)
}

extern "C" void kernel_launch(void* const* d_in, const int* in_sizes, int n_in,
                              void* d_out, int out_size, void* d_ws, size_t ws_size,
                              hipStream_t stream) {
    (void)n_in; (void)out_size; (void)ws_size;
    const void* z;
    const void* cbs;
    if (in_sizes[0] == 16777216) { z = d_in[0]; cbs = d_in[1]; }
    else                         { z = d_in[1]; cbs = d_in[0]; }

    float*  out      = (float*)d_out;
    float*  w2f      = (float*)d_ws;
    double* partials = (double*)((char*)d_ws + WS_PART_OFF);
    int*    flags    = (int*)((char*)d_ws + WS_FLAG_OFF);

    canary_kernel<<<1024, 256, 0, stream>>>(out);
    detect_kernel<<<1, 256, 0, stream>>>((const u16*)z, (const u16*)cbs, flags);
    w2_kernel<<<16, 256, 0, stream>>>(cbs, w2f, flags);
    rq_kernel<<<N_TOK / TM, 256, 0, stream>>>(z, cbs, w2f, out, partials, flags);
    loss_final<<<1, 256, 0, stream>>>(partials, out);
}

// Round 9
// 3066.148 us; speedup vs baseline: 2.4415x; 2.4415x over previous
//
#include <hip/hip_runtime.h>

// Residual VQ: N=65536, D=256, K=1024, 4 codebooks.
// Inputs: f32 (runtime-detected; bf16 fallback): z [N][D], cb [4][K][D].
// Output: FLOAT32 concat: quant_sum [N][D] | inds [N][4] | loss [1].
//
// Round 17: spill-free 8x8. R16 (B from global) failed decisively: per-lane
// VMEM broadcast, latency-bound, 7.7ms => B must stream through LDS. The
// LDS-bandwidth model: 4x8 tile = 2.07ms LDS floor; 8x8 = 1.37ms. R10/R12's
// 8x8 attempts died on the 128-VGPR wall (R12's residue: carried bval/bidx
// [16 regs] + edge spill). This round removes ALL carried per-thread state:
//  - argmin: per-kt epilogue reduces j in regs (transient), writes per-row
//    candidates to candv/candi (Wld overlay), cross-lane scan merges into
//    bestvL/bestiL[32] LDS running best across the 2 kt tiles. Ties: slot
//    scan uses full (v,idx) compare; cross-kt strict < keeps lower k ==
//    reference first-min (same equivalence as prior rounds).
//  - q: global RMW (R12-proven bit chain: cb0 writes 0+s, else read+add+w).
//  - r2: LDS read in epilogue (R11-proven).
//  Inner live set: acc64 + av32 + bv4 + addr ~= 112 <= 128 => no spill.
//  LDS 70,528 B (cand + dred overlay Wld) => 2 blocks/CU.
//  - Geometry/math == R12 (bitwise-verified absmax 0.0): TM=32, TK=512,
//    DC=16, WST=18; sequential fmaf d=0..255 (dc->dd->elem), np-pairwise
//    r2/w2, dist=fl(fl(r2-2dot)+w2), j-outer/i-inner k-ascending epilogue,
//    elementwise ST dance, f64 loss tree.
//  - Predicted: VGPR 112-124, FETCH 150-250MB, WRITE 300-340MB (no spill
//    signature), dur ~2.0-2.4ms rocprof, VALUBusy 60-70%.
// Rules: no __shfl, single instantiation, LDS-tree reductions, canary.

#define N_TOK 65536
#define DIM   256
#define KCB   1024
#define NCBK  4

#define TM  32          // rows per block
#define TK  512         // codes per k-tile (2 tiles per codebook)
#define DC  16          // d-chunk per W stage
#define RST 260         // f32 LDS stride, residual rows (16B-aligned)
#define WST 18          // f32 LDS stride, W rows (==2 mod 32: free 2-way, 8B-aligned)

#define QS_F   ((size_t)N_TOK * DIM)             // 16777216 f32 elements
#define IDX_F  QS_F
#define IDXE_F (IDX_F + (size_t)N_TOK * NCBK)    // 17039360
#define LOSS_F IDXE_F                            // 17039360

// d_ws: float w2f[4096] @0 | double partials[2048] @16384 | int flags[2] @32768
#define WS_PART_OFF 16384
#define WS_FLAG_OFF 32768

typedef unsigned short u16;
typedef unsigned int   u32;

__device__ __forceinline__ float bf2f(u32 h) { return __uint_as_float(h << 16); }

__device__ __forceinline__ float getv(const void* base, int f32in, size_t elt) {
    if (f32in) return ((const float*)base)[elt];
    return bf2f(((const u16*)base)[elt]);
}

// All call sites pass elt % 8 == 0 => 32B (f32) / 16B (bf16) aligned.
__device__ __forceinline__ void load8(const void* base, int f32in, size_t elt,
                                      float* f) {
    if (f32in) {
        const float4* p = (const float4*)((const float*)base + elt);
        float4 a = p[0], b = p[1];
        f[0] = a.x; f[1] = a.y; f[2] = a.z; f[3] = a.w;
        f[4] = b.x; f[5] = b.y; f[6] = b.z; f[7] = b.w;
    } else {
        uint4 q = *(const uint4*)((const u16*)base + elt);
        f[0] = bf2f(q.x & 0xffffu); f[1] = bf2f(q.x >> 16);
        f[2] = bf2f(q.y & 0xffffu); f[3] = bf2f(q.y >> 16);
        f[4] = bf2f(q.z & 0xffffu); f[5] = bf2f(q.z >> 16);
        f[6] = bf2f(q.w & 0xffffu); f[7] = bf2f(q.w >> 16);
    }
}

// canary: stamp f32 index region + loss with 512.0f (decodable no-op signal)
__global__ void canary_kernel(float* out) {
    int gid = blockIdx.x * 256 + threadIdx.x;
    size_t pos = IDX_F + (size_t)gid;
    if (pos < IDXE_F) out[pos] = 512.0f;
    if (gid == 0) out[LOSS_F] = 512.0f;
}

// dtype detect (bf16 vs f32), proven in rounds 7/8
__global__ void detect_kernel(const u16* z16, const u16* cb16, int* flags) {
    __shared__ int s0[256], s1[256];
    int tid = threadIdx.x;
    u32 a = z16[tid],  ea = (a >> 7) & 0xffu;
    u32 b = cb16[tid], eb = (b >> 7) & 0xffu;
    s0[tid] = ((ea >= 90u && ea <= 140u) || ((a & 0x7fffu) == 0u)) ? 1 : 0;
    s1[tid] = ((eb >= 90u && eb <= 140u) || ((b & 0x7fffu) == 0u)) ? 1 : 0;
    __syncthreads();
    for (int st = 128; st > 0; st >>= 1) {
        if (tid < st) { s0[tid] += s0[tid + st]; s1[tid] += s1[tid + st]; }
        __syncthreads();
    }
    if (tid == 0) { flags[0] = (s0[0] < 218) ? 1 : 0;   // 1 => f32
                    flags[1] = (s1[0] < 218) ? 1 : 0; }
}

// numpy pairwise sum-of-squares, one 128 block, AVX512 W=16 order
__device__ __forceinline__ float np128_sq_g(const void* base, int f32in, size_t off) {
    float S[16];
    #pragma unroll
    for (int l = 0; l < 16; ++l) {
        float A[8];
        #pragma unroll
        for (int j = 0; j < 8; ++j) {
            float x = getv(base, f32in, off + 16 * j + l);
            A[j] = x * x;
        }
        S[l] = ((A[0] + A[1]) + (A[2] + A[3])) + ((A[4] + A[5]) + (A[6] + A[7]));
    }
    float B1[8], B2[4];
    #pragma unroll
    for (int l = 0; l < 8; ++l) B1[l] = S[l] + S[l + 8];
    #pragma unroll
    for (int l = 0; l < 4; ++l) B2[l] = B1[l] + B1[l + 4];
    return (B2[0] + B2[2]) + (B2[1] + B2[3]);
}

__device__ __forceinline__ float np128_sq_lds(const float* a) {
    float S[16];
    #pragma unroll
    for (int l = 0; l < 16; ++l) {
        float A[8];
        #pragma unroll
        for (int j = 0; j < 8; ++j) { float x = a[16 * j + l]; A[j] = x * x; }
        S[l] = ((A[0] + A[1]) + (A[2] + A[3])) + ((A[4] + A[5]) + (A[6] + A[7]));
    }
    float B1[8], B2[4];
    #pragma unroll
    for (int l = 0; l < 8; ++l) B1[l] = S[l] + S[l + 8];
    #pragma unroll
    for (int l = 0; l < 4; ++l) B2[l] = B1[l] + B1[l + 4];
    return (B2[0] + B2[2]) + (B2[1] + B2[3]);
}

__global__ void w2_kernel(const void* cbs, float* w2f, const int* flags) {
    int kf = blockIdx.x * 256 + threadIdx.x;      // 0..4095
    const int fc = flags[1];
    size_t base = (size_t)kf * DIM;
    w2f[kf] = np128_sq_g(cbs, fc, base) + np128_sq_g(cbs, fc, base + 128);
}

__global__ __launch_bounds__(256, 2)
void rq_kernel(const void* z, const void* cbs, const float* w2f,
               float* out, double* partials, const int* flags) {
    __shared__ float  Rld[TM * RST];              // 33280 B
    __shared__ __align__(16) float Wld[TK * WST]; // 36864 B (overlays below)
    __shared__ float  r2s[TM];                    //   128 B
    __shared__ float  bestvL[TM];                 //   128 B
    __shared__ int    bestiL[TM];                 //   128 B => 70528 B total
                                                  //  => 2 blocks/CU

    // Overlays into Wld (time-disjoint with staged W data):
    //  - candv/candi: live only between post-kt barrier and merge barrier.
    //  - dred: live only after the final dance (Wld fully dead).
    float*  candv = Wld;                          // [32][65] floats
    int*    candi = (int*)(Wld + TM * 65);        // [32][65] ints
    double* dred  = (double*)Wld;                 // [256] doubles

    const int fz = flags[0], fc = flags[1];
    const int tid  = threadIdx.x;
    const int tx   = tid & 31;              // code lane
    const int ty   = tid >> 5;              // 0..7
    const int rowg = ty & 3;                // row group: rows rowg+4i, i=0..7
    const int cg   = ty >> 2;               // code half: codes tx+32j+256cg
    const int sl   = tx + 32 * cg;          // candidate slot 0..63
    const int row0 = blockIdx.x * TM;

    // staging constants: flat = it*256+tid -> k = it*128+(tid>>1), dp = (tid&1)*8
    const int stg_k0 = tid >> 1;
    const int stg_dp = (tid & 1) * 8;

    for (int it = 0; it < 4; ++it) {
        int flat = it * 256 + tid;
        int r = flat >> 5, c8 = flat & 31;
        float f[8];
        load8(z, fz, (size_t)(row0 + r) * DIM + c8 * 8, f);
        int base = r * RST + c8 * 8;
        #pragma unroll
        for (int e = 0; e < 8; ++e) Rld[base + e] = f[e];
    }
    double lsum = 0.0;

    for (int cb = 0; cb < NCBK; ++cb) {
        const size_t cbW = (size_t)cb * KCB * DIM;
        const float* w2c = w2f + cb * KCB;

        __syncthreads();                     // Rld settled (stage or prev dance)
        if (tid < TM) {                      // r2 = np pairwise sum(r*r)
            const float* a = &Rld[tid * RST];
            r2s[tid] = np128_sq_lds(a) + np128_sq_lds(a + 128);
        }
        __syncthreads();

        for (int kt = 0; kt < KCB / TK; ++kt) {          // 2 tiles of 512 codes
            float acc[8][8];                 // sequential-d f32 chains
            #pragma unroll
            for (int i = 0; i < 8; ++i)
                #pragma unroll
                for (int j = 0; j < 8; ++j) acc[i][j] = 0.f;

            for (int dc = 0; dc < DIM / DC; ++dc) {      // 16 chunks of 16 d
                __syncthreads();             // prior Wld readers done
                #pragma unroll
                for (int it = 0; it < 4; ++it) {   // stage [512]x[16] W chunk
                    int k  = it * 128 + stg_k0;    // 0..511
                    float f[8];
                    load8(cbs, fc, cbW + (size_t)(kt * TK + k) * DIM + dc * DC + stg_dp, f);
                    int wb = k * WST + stg_dp;     // even => b64-aligned
                    *(float2*)&Wld[wb]     = make_float2(f[0], f[1]);
                    *(float2*)&Wld[wb + 2] = make_float2(f[2], f[3]);
                    *(float2*)&Wld[wb + 4] = make_float2(f[4], f[5]);
                    *(float2*)&Wld[wb + 6] = make_float2(f[6], f[7]);
                }
                __syncthreads();

                #pragma unroll
                for (int dd = 0; dd < DC / 4; ++dd) {
                    float av[8][4];
                    #pragma unroll
                    for (int i = 0; i < 8; ++i) {
                        const float4 va = *(const float4*)
                            &Rld[(rowg + 4 * i) * RST + dc * DC + dd * 4];
                        av[i][0] = va.x; av[i][1] = va.y;
                        av[i][2] = va.z; av[i][3] = va.w;
                    }
                    #pragma unroll
                    for (int j = 0; j < 8; ++j) {
                        const int c = tx + 32 * j + 256 * cg;
                        const float2* wp = (const float2*)&Wld[c * WST + dd * 4];
                        const float2 b01 = wp[0];
                        const float2 b23 = wp[1];
                        #pragma unroll
                        for (int i = 0; i < 8; ++i) {
                            float s = acc[i][j];
                            s = fmaf(av[i][0], b01.x, s);   // d ascending:
                            s = fmaf(av[i][1], b01.y, s);   // BLAS sgemm
                            s = fmaf(av[i][2], b23.x, s);   // sequential-k
                            s = fmaf(av[i][3], b23.y, s);   // FMA chain
                            acc[i][j] = s;
                        }
                    }
                }
            }
            // per-kt epilogue: dist = fl(fl(r2-2dot)+w2), first-index ties.
            // bval/bidx are TRANSIENT here (not carried across kt) -> no
            // loop-carried register pressure in the dc loop.
            __syncthreads();                 // all Wld reads done -> overlay safe
            {
                float r2t[8];
                #pragma unroll
                for (int i = 0; i < 8; ++i) r2t[i] = r2s[rowg + 4 * i];
                float bval[8]; int bidx[8];
                #pragma unroll
                for (int i = 0; i < 8; ++i) { bval[i] = __uint_as_float(0x7f7fffffu); bidx[i] = 0; }
                #pragma unroll
                for (int j = 0; j < 8; ++j) {
                    const int k = kt * TK + tx + 32 * j + 256 * cg;
                    const float w2k = w2c[k];
                    #pragma unroll
                    for (int i = 0; i < 8; ++i) {
                        float t2   = r2t[i] - 2.0f * acc[i][j];
                        float dist = t2 + w2k;
                        if (dist < bval[i] || (dist == bval[i] && k < bidx[i])) {
                            bval[i] = dist; bidx[i] = k;
                        }
                    }
                }
                #pragma unroll
                for (int i = 0; i < 8; ++i) {
                    int r = rowg + 4 * i;
                    candv[r * 65 + sl] = bval[i];
                    candi[r * 65 + sl] = bidx[i];
                }
            }
            __syncthreads();                 // cand visible
            if (tid < TM) {
                float best = candv[tid * 65];
                int   bi   = candi[tid * 65];
                for (int t = 1; t < 64; ++t) {
                    float v = candv[tid * 65 + t];
                    int  ix = candi[tid * 65 + t];
                    if (v < best || (v == best && ix < bi)) { best = v; bi = ix; }
                }
                // cross-kt merge: kt1 codes all > kt0 codes, so strict <
                // keeps the lower index on value ties (== reference).
                if (kt == 0 || best < bestvL[tid]) {
                    bestvL[tid] = best; bestiL[tid] = bi;
                }
            }
            __syncthreads();                 // merge done; next kt may restage
        }

        // index output (bestiL final for this cb)
        if (tid < TM) {
            size_t pos = IDX_F + (size_t)(row0 + tid) * NCBK + cb;
            if (pos < IDXE_F) out[pos] = (float)bestiL[tid];
        }

        // straight-through dance, elementwise f32 (np bit order):
        // t = zq - r; s = r + t; r' = r - s; q += s; loss += t^2
        // q lives in GLOBAL out[]: cb==0 writes (0+s), else read+add+write
        // (same f32 chain (((0+s1)+s2)+s3)+s4 as a register q).
        #pragma unroll
        for (int it = 0; it < 4; ++it) {
            int flat = it * 256 + tid;
            int r = flat >> 5, c8 = flat & 31;
            int kb = bestiL[r];
            float f[8];
            load8(cbs, fc, cbW + (size_t)kb * DIM + c8 * 8, f);
            int base = r * RST + c8 * 8;
            size_t pos = (size_t)(row0 + r) * DIM + c8 * 8;
            float qv[8];
            if (cb == 0) {
                #pragma unroll
                for (int e = 0; e < 8; ++e) qv[e] = 0.0f;
            } else {
                float4 o0 = *(const float4*)&out[pos];
                float4 o1 = *(const float4*)&out[pos + 4];
                qv[0] = o0.x; qv[1] = o0.y; qv[2] = o0.z; qv[3] = o0.w;
                qv[4] = o1.x; qv[5] = o1.y; qv[6] = o1.z; qv[7] = o1.w;
            }
            #pragma unroll
            for (int e = 0; e < 8; ++e) {
                float rv = Rld[base + e];
                float t  = f[e] - rv;
                float s  = rv + t;
                float rn = rv - s;
                Rld[base + e] = rn;
                qv[e] = qv[e] + s;
                lsum += (double)t * (double)t;
            }
            *(float4*)&out[pos]     = make_float4(qv[0], qv[1], qv[2], qv[3]);
            *(float4*)&out[pos + 4] = make_float4(qv[4], qv[5], qv[6], qv[7]);
        }
        __syncthreads();                     // dance done before next cb
    }

    // loss: per-block f64 LDS tree (dred overlays Wld; Wld dead here)
    dred[tid] = lsum;
    __syncthreads();
    for (int s = 128; s > 0; s >>= 1) {
        if (tid < s) dred[tid] += dred[tid + s];
        __syncthreads();
    }
    if (tid == 0) partials[blockIdx.x] = dred[0];
}

__global__ void loss_final(const double* partials, float* out) {
    __shared__ double sred[256];
    int tid = threadIdx.x;
    double s = 0.0;
    for (int q = 0; q < 8; ++q) s += partials[tid + 256 * q];
    sred[tid] = s;
    __syncthreads();
    for (int st = 128; st > 0; st >>= 1) {
        if (tid < st) sred[tid] += sred[tid + st];
        __syncthreads();
    }
    if (tid == 0)
        out[LOSS_F] = (float)(2.0 * sred[0] / 16777216.0);  // 2*S/(N*D)
}

extern "C" void kernel_launch(void* const* d_in, const int* in_sizes, int n_in,
                              void* d_out, int out_size, void* d_ws, size_t ws_size,
                              hipStream_t stream) {
    (void)n_in; (void)out_size; (void)ws_size;
    const void* z;
    const void* cbs;
    if (in_sizes[0] == 16777216) { z = d_in[0]; cbs = d_in[1]; }
    else                         { z = d_in[1]; cbs = d_in[0]; }

    float*  out      = (float*)d_out;
    float*  w2f      = (float*)d_ws;
    double* partials = (double*)((char*)d_ws + WS_PART_OFF);
    int*    flags    = (int*)((char*)d_ws + WS_FLAG_OFF);

    canary_kernel<<<1024, 256, 0, stream>>>(out);
    detect_kernel<<<1, 256, 0, stream>>>((const u16*)z, (const u16*)cbs, flags);
    w2_kernel<<<16, 256, 0, stream>>>(cbs, w2f, flags);
    rq_kernel<<<N_TOK / TM, 256, 0, stream>>>(z, cbs, w2f, out, partials, flags);
    loss_final<<<1, 256, 0, stream>>>(partials, out);
}